// Round 7
// baseline (621.344 us; speedup 1.0000x reference)
//
#include <hip/hip_runtime.h>

#define NN 50000
#define EE 800000
#define HEADS 8
#define NEG 0.2f
#define BN_EPS 1e-5f
#define SCAN_B 196   // ceil(NN/256)

typedef unsigned int uint;
typedef unsigned short ushort;

typedef __bf16 bf16x8 __attribute__((ext_vector_type(8)));
typedef float f32x4 __attribute__((ext_vector_type(4)));

__device__ __forceinline__ float bflo(uint u) { return __uint_as_float(u << 16); }
__device__ __forceinline__ float bfhi(uint u) { return __uint_as_float(u & 0xffff0000u); }
__device__ __forceinline__ float bf1(ushort u) { return __uint_as_float(((uint)u) << 16); }
__device__ __forceinline__ ushort f2bf(float f) {
  uint u = __float_as_uint(f);
  u += 0x7fff + ((u >> 16) & 1);   // RTNE
  return (ushort)(u >> 16);
}
__device__ __forceinline__ uint pk2(float a, float b) {
  return (uint)f2bf(a) | ((uint)f2bf(b) << 16);
}
__device__ __forceinline__ float eluf(float v) { return v > 0.f ? v : expm1f(v); }

// ---------------------------------------------------------------- per-block dtype detectors
// Recomputed by every block that needs them (~256 L2-hot loads) — removes the
// flags-buffer dependency chain and the k_detect dispatch.
__device__ __forceinline__ int blk_detect_bf16(const uint* __restrict__ xw) {
  __shared__ int s_bf;
  int t = threadIdx.x;
  if (t < 64) {
    int good = 0;
#pragma unroll
    for (int j = 0; j < 4; ++j) {
      uint lo = xw[t * 4 + j] & 0xffffu;
      uint ex = (lo >> 7) & 0xffu;
      good += (ex >= 110u && ex <= 140u) ? 1 : 0;
    }
    for (int o = 32; o; o >>= 1) good += __shfl_down(good, o);
    if (t == 0) s_bf = (good >= 128) ? 1 : 0;
  }
  __syncthreads();
  return s_bf;
}

__device__ __forceinline__ int blk_detect_i64(const int* __restrict__ ew) {
  __shared__ int s_i64;
  int t = threadIdx.x;
  if (t < 64) {
    int zeros = 0;
#pragma unroll
    for (int j = 0; j < 4; ++j)
      zeros += (ew[2 * (t * 4 + j) + 1] == 0) ? 1 : 0;
    for (int o = 32; o; o >>= 1) zeros += __shfl_down(zeros, o);
    if (t == 0) s_i64 = (zeros >= 200) ? 1 : 0;
  }
  __syncthreads();
  return s_i64;
}

// ---------------------------------------------------------------- prep: params + all weight transposes
// blocks 0..10: param gather -> f32 block P.
// P layout (f32): att_s@0 att_d@256 c_bias@512 g_norm@768 b_norm@1024
//                 b_down@1280 g_down@1344 bb_down@1408 b_up@1472 g_up@1728 bb_up@1984
// blocks 11..26: W_lin^T -> bt1        (256x256)
// blocks 27..42: W_res^T -> bt1+65536  (256x256)
// blocks 43..50: W_down^T -> bt2       (256x64, D=128 zero-pad)
// blocks 51..54: W_up^T  -> bt3        (64x256)
__global__ __launch_bounds__(256)
void k_prep(const void* __restrict__ x,
            const void* p0, const void* p1, const void* p2, const void* p3,
            const void* p4, const void* p5, const void* p6, const void* p7,
            const void* p8, const void* p9, const void* p10,
            const void* W_lin, const void* W_res, const void* W_down, const void* W_up,
            float* __restrict__ P, ushort* __restrict__ bt1,
            ushort* __restrict__ bt2, ushort* __restrict__ bt3) {
  __shared__ ushort tile[64][65];
  int bf = blk_detect_bf16((const uint*)x);
  int b = blockIdx.x, t = threadIdx.x;
  if (b < 11) {
    const void* srcs[11] = {p0, p1, p2, p3, p4, p5, p6, p7, p8, p9, p10};
    const int sz[11]  = {256, 256, 256, 256, 256, 64, 64, 64, 256, 256, 256};
    const int off[11] = {0, 256, 512, 768, 1024, 1280, 1344, 1408, 1472, 1728, 1984};
    if (t < sz[b]) {
      const void* s = srcs[b];
      P[off[b] + t] = bf ? bf1(((const ushort*)s)[t]) : ((const float*)s)[t];
    }
    return;
  }
  const void* src; ushort* dst; int R, C, D, rb, cb;
  if (b < 27)      { int u = b - 11; src = W_lin;  dst = bt1;         R = 256; C = 256; D = 256; rb = u & 3; cb = u >> 2; }
  else if (b < 43) { int u = b - 27; src = W_res;  dst = bt1 + 65536; R = 256; C = 256; D = 256; rb = u & 3; cb = u >> 2; }
  else if (b < 51) { int u = b - 43; src = W_down; dst = bt2;         R = 256; C = 64;  D = 128; rb = u & 3; cb = u >> 2; }
  else             { int u = b - 51; src = W_up;   dst = bt3;         R = 64;  C = 256; D = 256; rb = 0;     cb = u; }
  int r0 = rb * 64, c0 = cb * 64;
  int tr = t >> 6, tc = t & 63;
#pragma unroll
  for (int i = 0; i < 16; ++i) {
    int rl = tr + i * 4;
    int r = r0 + rl, c = c0 + tc;
    float v = 0.f;
    if (r < R && c < C)
      v = bf ? bf1(((const ushort*)src)[(size_t)r * C + c])
             : ((const float*)src)[(size_t)r * C + c];
    tile[rl][tc] = f2bf(v);
  }
  __syncthreads();
#pragma unroll
  for (int i = 0; i < 16; ++i) {
    int cl = tr + i * 4;
    int rl = tc;
    int c = c0 + cl, r = r0 + rl;
    if (c < D && r < R)
      dst[(size_t)c * R + r] = (c < C) ? tile[rl][cl] : (ushort)0;
  }
}

// ---------------------------------------------------------------- edges -> canonical int32 + degree count
__global__ __launch_bounds__(256)
void k_edges(const int* __restrict__ raw, int* __restrict__ sc, int* __restrict__ dc,
             int* __restrict__ count) {
  int i64 = blk_detect_i64(raw);
  int e = blockIdx.x * 256 + threadIdx.x;
  if (e >= EE) return;
  int s, d;
  if (i64) { s = raw[2 * e]; d = raw[2 * (EE + e)]; }   // int64 lo words
  else     { s = raw[e];     d = raw[EE + e]; }
  if ((uint)s >= NN) s = 0;
  if ((uint)d >= NN) d = 0;
  sc[e] = s; dc[e] = d;
  atomicAdd(&count[d], 1);
}

// ---------------------------------------------------------------- GEMM (MFMA bf16)
// C[M,*] = A[M,K] @ Bt[n,K]^T. grid = (m_blocks); each block loops nIter n-tiles of 128
// over the FULL K-loop, so A-tile re-reads hit the same XCD's L2 (no cross-XCD dup).
// aMode 0: A is bf16.  aMode 1: A dtype self-detected (f32 -> convert in staging).
// aMode 2: A is bf16 + BN+ELU applied in staging (scale/shift from bnsums/bng/bnb, channel = K index).
// mode 0: bf16 stores split: cols<256 -> o_xh, cols>=256 -> o_xres
// mode 1: bf16 store to o_bf [M,NC] (guard gc<NC) + f32 bias add
__global__ __launch_bounds__(256)
void k_gemm(const void* __restrict__ A, const ushort* __restrict__ Bt,
            int aMode, int nIter, int M, int K, int mode,
            ushort* __restrict__ o_xh, ushort* __restrict__ o_xres,
            ushort* __restrict__ o_bf, int NC, const float* __restrict__ bias,
            const float* __restrict__ bnsums, const float* __restrict__ bng,
            const float* __restrict__ bnb) {
  __shared__ __align__(16) ushort As[128 * 32];
  __shared__ __align__(16) ushort Bs[128 * 32];
  __shared__ float scs[256], shs[256];
  int t = threadIdx.x;
  int l = t & 63, w = t >> 6;
  int wr = w >> 1, wc = w & 1;
  int lr = l & 15, lq = l >> 4;
  int m0 = blockIdx.x * 128;
  const ushort* Ab = (const ushort*)A;
  const float*  Af = (const float*)A;

  int af32 = 0;
  if (aMode == 1) af32 = blk_detect_bf16((const uint*)A) ? 0 : 1;
  if (aMode == 2) {
    if (t < K) {
      const float invN = 1.0f / NN;
      float mean = bnsums[t] * invN;
      float var = bnsums[K + t] * invN - mean * mean;
      float sc = bng[t] * rsqrtf(var + BN_EPS);
      scs[t] = sc;
      shs[t] = bnb[t] - mean * sc;
    }
    // first loop-top __syncthreads covers visibility
  }

  for (int nc = 0; nc < nIter; ++nc) {
    int n0 = nc * 128;
    f32x4 acc[4][4];
#pragma unroll
    for (int i = 0; i < 4; ++i)
#pragma unroll
      for (int j = 0; j < 4; ++j) acc[i][j] = (f32x4){0.f, 0.f, 0.f, 0.f};

    for (int kt = 0; kt < K; kt += 32) {
      __syncthreads();
#pragma unroll
      for (int r = 0; r < 2; ++r) {
        int ci = r * 256 + t;
        int m = ci >> 2, ko = (ci & 3) << 3;
        int gm = m0 + m; gm = gm < M ? gm : M - 1;
        if (aMode == 1 && af32) {
          float4 u0 = *(const float4*)(Af + (size_t)gm * K + kt + ko);
          float4 u1 = *(const float4*)(Af + (size_t)gm * K + kt + ko + 4);
          uint4 o;
          o.x = pk2(u0.x, u0.y); o.y = pk2(u0.z, u0.w);
          o.z = pk2(u1.x, u1.y); o.w = pk2(u1.z, u1.w);
          *(uint4*)(&As[m * 32 + ko]) = o;
        } else if (aMode == 2) {
          uint4 q = *(const uint4*)(Ab + (size_t)gm * K + kt + ko);
          int cb = kt + ko;
          float v0 = eluf(bflo(q.x) * scs[cb + 0] + shs[cb + 0]);
          float v1 = eluf(bfhi(q.x) * scs[cb + 1] + shs[cb + 1]);
          float v2 = eluf(bflo(q.y) * scs[cb + 2] + shs[cb + 2]);
          float v3 = eluf(bfhi(q.y) * scs[cb + 3] + shs[cb + 3]);
          float v4 = eluf(bflo(q.z) * scs[cb + 4] + shs[cb + 4]);
          float v5 = eluf(bfhi(q.z) * scs[cb + 5] + shs[cb + 5]);
          float v6 = eluf(bflo(q.w) * scs[cb + 6] + shs[cb + 6]);
          float v7 = eluf(bfhi(q.w) * scs[cb + 7] + shs[cb + 7]);
          uint4 o;
          o.x = pk2(v0, v1); o.y = pk2(v2, v3);
          o.z = pk2(v4, v5); o.w = pk2(v6, v7);
          *(uint4*)(&As[m * 32 + ko]) = o;
        } else {
          *(uint4*)(&As[m * 32 + ko]) = *(const uint4*)(Ab + (size_t)gm * K + kt + ko);
        }
        *(uint4*)(&Bs[m * 32 + ko]) = *(const uint4*)(Bt + (size_t)(n0 + m) * K + kt + ko);
      }
      __syncthreads();
      bf16x8 af[4], bf[4];
#pragma unroll
      for (int i = 0; i < 4; ++i) {
        af[i] = *(const bf16x8*)(&As[(wr * 64 + i * 16 + lr) * 32 + lq * 8]);
        bf[i] = *(const bf16x8*)(&Bs[(wc * 64 + i * 16 + lr) * 32 + lq * 8]);
      }
#pragma unroll
      for (int i = 0; i < 4; ++i)
#pragma unroll
        for (int j = 0; j < 4; ++j)
          acc[i][j] = __builtin_amdgcn_mfma_f32_16x16x32_bf16(af[i], bf[j], acc[i][j], 0, 0, 0);
    }

    // C/D layout: col=lane&15, row=(lane>>4)*4+reg  [m89/m91]
#pragma unroll
    for (int i = 0; i < 4; ++i) {
      int gr0 = m0 + wr * 64 + i * 16 + lq * 4;
#pragma unroll
      for (int j = 0; j < 4; ++j) {
        int gc = n0 + wc * 64 + j * 16 + lr;
#pragma unroll
        for (int r = 0; r < 4; ++r) {
          int row = gr0 + r;
          if (row >= M) continue;
          float v = acc[i][j][r];
          if (mode == 0) {
            if (gc < 256) o_xh[(size_t)row * 256 + gc] = f2bf(v);
            else          o_xres[(size_t)row * 256 + (gc - 256)] = f2bf(v);
          } else {
            if (gc < NC) o_bf[(size_t)row * NC + gc] = f2bf(v + bias[gc]);
          }
        }
      }
    }
  }
}

// ---------------------------------------------------------------- attention dots
__global__ void k_attn(const ushort* __restrict__ xh, const float* __restrict__ P,
                       float* __restrict__ a_src, float* __restrict__ a_dst) {
  int id = blockIdx.x * 256 + threadIdx.x;
  if (id >= NN * HEADS) return;
  int n = id >> 3, h = id & 7;
  const uint4* xr = (const uint4*)(xh + (size_t)n * 256 + h * 32);
  const float4* pa = (const float4*)(P + h * 32);
  const float4* pd = (const float4*)(P + 256 + h * 32);
  float s = 0.f, d = 0.f;
#pragma unroll
  for (int j = 0; j < 4; ++j) {
    uint4 q = xr[j];
    float4 a0 = pa[2 * j], a1 = pa[2 * j + 1];
    float4 d0 = pd[2 * j], d1 = pd[2 * j + 1];
    float x0 = bflo(q.x), x1 = bfhi(q.x), x2 = bflo(q.y), x3 = bfhi(q.y);
    float x4 = bflo(q.z), x5 = bfhi(q.z), x6 = bflo(q.w), x7 = bfhi(q.w);
    s += x0 * a0.x + x1 * a0.y + x2 * a0.z + x3 * a0.w
       + x4 * a1.x + x5 * a1.y + x6 * a1.z + x7 * a1.w;
    d += x0 * d0.x + x1 * d0.y + x2 * d0.z + x3 * d0.w
       + x4 * d1.x + x5 * d1.y + x6 * d1.z + x7 * d1.w;
  }
  a_src[id] = s; a_dst[id] = d;
}

// ---------------------------------------------------------------- hierarchical scan (3 kernels)
__global__ void k_scan_bs(const int* __restrict__ count, int* __restrict__ bsum) {
  __shared__ int s[256];
  int i = blockIdx.x * 256 + threadIdx.x;
  s[threadIdx.x] = (i < NN) ? count[i] : 0;
  __syncthreads();
  for (int off = 128; off > 0; off >>= 1) {
    if (threadIdx.x < off) s[threadIdx.x] += s[threadIdx.x + off];
    __syncthreads();
  }
  if (threadIdx.x == 0) bsum[blockIdx.x] = s[0];
}

__global__ void k_scan_top(const int* __restrict__ bsum, int* __restrict__ boff,
                           int* __restrict__ rowptr) {
  __shared__ int s[256];
  int t = threadIdx.x;
  int v = (t < SCAN_B) ? bsum[t] : 0;
  s[t] = v;
  __syncthreads();
  for (int off = 1; off < 256; off <<= 1) {
    int u = (t >= off) ? s[t - off] : 0;
    __syncthreads();
    s[t] += u;
    __syncthreads();
  }
  boff[t] = s[t] - v;
  if (t == 255) rowptr[NN] = s[255];
}

__global__ void k_scan_wr(const int* __restrict__ count, const int* __restrict__ boff,
                          int* __restrict__ rowptr, int* __restrict__ rowwork) {
  __shared__ int s[256];
  int b = blockIdx.x, t = threadIdx.x;
  int i = b * 256 + t;
  int v = (i < NN) ? count[i] : 0;
  s[t] = v;
  __syncthreads();
  for (int off = 1; off < 256; off <<= 1) {
    int u = (t >= off) ? s[t - off] : 0;
    __syncthreads();
    s[t] += u;
    __syncthreads();
  }
  if (i < NN) {
    int ex = boff[b] + s[t] - v;
    rowptr[i] = ex;
    rowwork[i] = ex;
  }
}

// ---------------------------------------------------------------- scatter edges into CSR order
__global__ void k_scatter(const int* __restrict__ sc, const int* __restrict__ dc,
                          int* __restrict__ rowwork, int* __restrict__ perm_src) {
  int e = blockIdx.x * 256 + threadIdx.x;
  if (e >= EE) return;
  int pos = atomicAdd(&rowwork[dc[e]], 1);
  perm_src[pos] = sc[e];
}

// ---------------------------------------------------------------- gather aggregation
__global__ __launch_bounds__(256)
void k_aggregate(const int* __restrict__ rowptr, const int* __restrict__ perm_src,
                 const float* __restrict__ a_src, const float* __restrict__ a_dst,
                 const ushort* __restrict__ xh, const ushort* __restrict__ xres,
                 const float* __restrict__ bias, ushort* __restrict__ outb) {
  int n = blockIdx.x * 4 + (threadIdx.x >> 6);
  int l = threadIdx.x & 63;
  if (n >= NN) return;
  int half = l >> 5;           // 0: even edges, 1: odd edges
  int q = l & 31;              // channels 8q..8q+7
  int h = q >> 2;              // head
  float ad = a_dst[n * 8 + h];
  int st = rowptr[n], en = rowptr[n + 1];
  float a0 = 0.f, a1 = 0.f, a2 = 0.f, a3 = 0.f;
  float a4 = 0.f, a5 = 0.f, a6 = 0.f, a7 = 0.f, sum = 0.f;
  int p = st + half;
  int s_c = 0; float e_c = 0.f; uint4 x_c = {0, 0, 0, 0};
  if (p < en) {
    s_c = perm_src[p];
    e_c = a_src[s_c * 8 + h];
    x_c = *(const uint4*)(xh + (size_t)s_c * 256 + q * 8);
  }
  for (; p < en; p += 2) {
    int pn = p + 2;
    int s_n = 0; float e_n = 0.f; uint4 x_n = {0, 0, 0, 0};
    if (pn < en) {
      s_n = perm_src[pn];
      e_n = a_src[s_n * 8 + h];
      x_n = *(const uint4*)(xh + (size_t)s_n * 256 + q * 8);
    }
    float v = e_c + ad;
    v = v > 0.f ? v : NEG * v;
    float wgt = __expf(fminf(v, 60.f));
    sum += wgt;
    a0 += wgt * bflo(x_c.x); a1 += wgt * bfhi(x_c.x);
    a2 += wgt * bflo(x_c.y); a3 += wgt * bfhi(x_c.y);
    a4 += wgt * bflo(x_c.z); a5 += wgt * bfhi(x_c.z);
    a6 += wgt * bflo(x_c.w); a7 += wgt * bfhi(x_c.w);
    s_c = s_n; e_c = e_n; x_c = x_n;
  }
  sum += __shfl_xor(sum, 32);
  a0 += __shfl_xor(a0, 32); a1 += __shfl_xor(a1, 32);
  a2 += __shfl_xor(a2, 32); a3 += __shfl_xor(a3, 32);
  a4 += __shfl_xor(a4, 32); a5 += __shfl_xor(a5, 32);
  a6 += __shfl_xor(a6, 32); a7 += __shfl_xor(a7, 32);
  if (half == 0) {
    float inv = 1.0f / (sum + 1e-16f);
    int cb = q * 8;
    float4 b0 = *(const float4*)(bias + cb);
    float4 b1 = *(const float4*)(bias + cb + 4);
    uint4 qr = *(const uint4*)(xres + (size_t)n * 256 + cb);
    uint4 pk;
    pk.x = pk2(a0 * inv + b0.x + bflo(qr.x), a1 * inv + b0.y + bfhi(qr.x));
    pk.y = pk2(a2 * inv + b0.z + bflo(qr.y), a3 * inv + b0.w + bfhi(qr.y));
    pk.z = pk2(a4 * inv + b1.x + bflo(qr.z), a5 * inv + b1.y + bfhi(qr.z));
    pk.w = pk2(a6 * inv + b1.z + bflo(qr.w), a7 * inv + b1.w + bfhi(qr.w));
    *(uint4*)(outb + (size_t)n * 256 + cb) = pk;
  }
}

// ---------------------------------------------------------------- BN stats: block partials + 64-way atomic fold
// sums[0,C)=sum, sums[C,2C)=sumsq; must be zeroed before launch. 64 blocks.
__global__ __launch_bounds__(256)
void k_stats_p(const ushort* __restrict__ x, float* __restrict__ sums, int n, int C) {
  __shared__ float4 redA[256];
  __shared__ float4 redB[256];
  int t = threadIdx.x, b = blockIdx.x;
  int W = C >> 2;            // uint2 columns per row
  int c4 = t & (W - 1);      // owns channels 4*c4 .. 4*c4+3
  int rl = t / W;
  int G = 256 / W;
  int rows = (n + 63) / 64;
  int r0 = b * rows, r1 = r0 + rows; if (r1 > n) r1 = n;
  const uint2* xu = (const uint2*)x;
  float s0 = 0, s1 = 0, s2 = 0, s3 = 0, q0 = 0, q1 = 0, q2 = 0, q3 = 0;
  for (int r = r0 + rl; r < r1; r += G) {
    uint2 v = xu[(size_t)r * W + c4];
    float v0 = bflo(v.x), v1 = bfhi(v.x), v2 = bflo(v.y), v3 = bfhi(v.y);
    s0 += v0; s1 += v1; s2 += v2; s3 += v3;
    q0 += v0 * v0; q1 += v1 * v1; q2 += v2 * v2; q3 += v3 * v3;
  }
  redA[t] = make_float4(s0, s1, s2, s3);
  redB[t] = make_float4(q0, q1, q2, q3);
  __syncthreads();
  for (int off = 128; off >= W; off >>= 1) {
    if (t < off) {
      float4 a = redA[t + off], c = redA[t];
      redA[t] = make_float4(c.x + a.x, c.y + a.y, c.z + a.z, c.w + a.w);
      float4 d = redB[t + off], e = redB[t];
      redB[t] = make_float4(e.x + d.x, e.y + d.y, e.z + d.z, e.w + d.w);
    }
    __syncthreads();
  }
  if (t < W) {
    float4 a = redA[t], d = redB[t];
    atomicAdd(&sums[4 * c4 + 0], a.x); atomicAdd(&sums[4 * c4 + 1], a.y);
    atomicAdd(&sums[4 * c4 + 2], a.z); atomicAdd(&sums[4 * c4 + 3], a.w);
    atomicAdd(&sums[C + 4 * c4 + 0], d.x); atomicAdd(&sums[C + 4 * c4 + 1], d.y);
    atomicAdd(&sums[C + 4 * c4 + 2], d.z); atomicAdd(&sums[C + 4 * c4 + 3], d.w);
  }
}

// ---------------------------------------------------------------- out = elu(bn1(og)) + elu(bn3(u_pre)) + x
__global__ void k_final(const ushort* __restrict__ upre, const float* __restrict__ sums3,
                        const ushort* __restrict__ og, const float* __restrict__ sums1,
                        const float* __restrict__ P, const void* __restrict__ xsrc,
                        void* __restrict__ outv) {
  int bf = blk_detect_bf16((const uint*)xsrc);
  int id = blockIdx.x * 256 + threadIdx.x;
  size_t base = (size_t)id * 4;
  if (base >= (size_t)NN * 256) return;
  int c = (int)(base & 255);
  const float invN = 1.0f / NN;
  float4 s3m = *(const float4*)(sums3 + c);
  float4 s3q = *(const float4*)(sums3 + 256 + c);
  float4 g3 = *(const float4*)(P + 1728 + c);
  float4 b3 = *(const float4*)(P + 1984 + c);
  float4 s1m = *(const float4*)(sums1 + c);
  float4 s1q = *(const float4*)(sums1 + 256 + c);
  float4 g1 = *(const float4*)(P + 768 + c);
  float4 b1 = *(const float4*)(P + 1024 + c);
  uint2 qu = *(const uint2*)(upre + base);
  uint2 qo = *(const uint2*)(og + base);
  float xv[4];
  if (bf) {
    uint2 qx = *(const uint2*)((const ushort*)xsrc + base);
    xv[0] = bflo(qx.x); xv[1] = bfhi(qx.x); xv[2] = bflo(qx.y); xv[3] = bfhi(qx.y);
  } else {
    float4 qx = *(const float4*)((const float*)xsrc + base);
    xv[0] = qx.x; xv[1] = qx.y; xv[2] = qx.z; xv[3] = qx.w;
  }
  float uv[4] = {bflo(qu.x), bfhi(qu.x), bflo(qu.y), bfhi(qu.y)};
  float ov[4] = {bflo(qo.x), bfhi(qo.x), bflo(qo.y), bfhi(qo.y)};
  float s3mv[4] = {s3m.x, s3m.y, s3m.z, s3m.w}, s3qv[4] = {s3q.x, s3q.y, s3q.z, s3q.w};
  float g3v[4] = {g3.x, g3.y, g3.z, g3.w}, b3v[4] = {b3.x, b3.y, b3.z, b3.w};
  float s1mv[4] = {s1m.x, s1m.y, s1m.z, s1m.w}, s1qv[4] = {s1q.x, s1q.y, s1q.z, s1q.w};
  float g1v[4] = {g1.x, g1.y, g1.z, g1.w}, b1v[4] = {b1.x, b1.y, b1.z, b1.w};
  float o[4];
#pragma unroll
  for (int j = 0; j < 4; ++j) {
    float m3 = s3mv[j] * invN;
    float v3 = s3qv[j] * invN - m3 * m3;
    float sc3 = g3v[j] * rsqrtf(v3 + BN_EPS);
    float u = eluf((uv[j] - m3) * sc3 + b3v[j]);
    float m1 = s1mv[j] * invN;
    float v1 = s1qv[j] * invN - m1 * m1;
    float sc1 = g1v[j] * rsqrtf(v1 + BN_EPS);
    float h1 = eluf((ov[j] - m1) * sc1 + b1v[j]);
    o[j] = u + h1 + xv[j];
  }
  if (bf) {
    uint2 pk;
    pk.x = pk2(o[0], o[1]);
    pk.y = pk2(o[2], o[3]);
    *(uint2*)((ushort*)outv + base) = pk;
  } else {
    *(float4*)((float*)outv + base) = make_float4(o[0], o[1], o[2], o[3]);
  }
}

// ================================================================ host
extern "C" void kernel_launch(void* const* d_in, const int* in_sizes, int n_in,
                              void* d_out, int out_size, void* d_ws, size_t ws_size,
                              hipStream_t stream) {
  const void* x      = d_in[0];
  const int*  ei     = (const int*)d_in[1];
  const void* W_lin  = d_in[2];
  const void* att_s  = d_in[3];
  const void* att_d  = d_in[4];
  const void* c_bias = d_in[5];
  const void* W_res  = d_in[6];
  const void* g_norm = d_in[7];
  const void* b_norm = d_in[8];
  const void* W_down = d_in[9];
  const void* b_down = d_in[10];
  const void* g_down = d_in[11];
  const void* bb_down= d_in[12];
  const void* W_up   = d_in[13];
  const void* b_up   = d_in[14];
  const void* g_up   = d_in[15];
  const void* bb_up  = d_in[16];

  char* ws = (char*)d_ws;
  size_t off = 0;
  auto alloc = [&](size_t bytes) -> char* {
    char* p = ws + off;
    off = (off + bytes + 255) & ~(size_t)255;
    return p;
  };
  // ---- zeroed region (atomic accumulators)
  int*   count  = (int*)alloc((size_t)NN * 4);
  float* sums1  = (float*)alloc(512 * 4);
  float* sums2  = (float*)alloc(128 * 4);
  float* sums3  = (float*)alloc(512 * 4);
  size_t zbytes = off;
  // ---- rest
  float* P      = (float*)alloc(2240 * 4);
  int* bsum     = (int*)alloc(256 * 4);
  int* boff     = (int*)alloc(256 * 4);
  int* rowptr   = (int*)alloc((size_t)(NN + 1) * 4);
  int* rowwork  = (int*)alloc((size_t)(NN + 1) * 4);
  int* src_c    = (int*)alloc((size_t)EE * 4);
  int* dst_c    = (int*)alloc((size_t)EE * 4);
  int* perm_src = (int*)alloc((size_t)EE * 4);
  ushort* bt1   = (ushort*)alloc((size_t)512 * 256 * 2);
  ushort* bt2   = (ushort*)alloc((size_t)128 * 256 * 2);  // rows 64..127 zero-padded
  ushort* bt3   = (ushort*)alloc((size_t)256 * 64 * 2);
  float* a_src  = (float*)alloc((size_t)NN * 8 * 4);
  float* a_dst  = (float*)alloc((size_t)NN * 8 * 4);
  ushort* xh    = (ushort*)alloc((size_t)NN * 256 * 2);
  ushort* xres  = (ushort*)alloc((size_t)NN * 256 * 2);
  ushort* og_b  = (ushort*)alloc((size_t)NN * 256 * 2);   // GAT output bf16 (lives to k_final)
  // ---- aliases (non-overlapping lifetimes)
  ushort* d_pre_b = xh;    // xh dead after k_aggregate; GEMM2 output [NN,64]
  ushort* u_pre_b = xres;  // xres dead after k_aggregate; GEMM3 output [NN,256]

  hipMemsetAsync(d_ws, 0, zbytes, stream);

  hipLaunchKernelGGL(k_prep, dim3(55), dim3(256), 0, stream, x,
                     att_s, att_d, c_bias, g_norm, b_norm, b_down, g_down, bb_down,
                     b_up, g_up, bb_up, W_lin, W_res, W_down, W_up, P, bt1, bt2, bt3);
  hipLaunchKernelGGL(k_edges, dim3((EE + 255) / 256), dim3(256), 0, stream,
                     ei, src_c, dst_c, count);

  // GEMM1: [xh | xres] = x @ [W_lin | W_res]  (n-loop in-block for same-XCD A reuse)
  hipLaunchKernelGGL(k_gemm, dim3(391), dim3(256), 0, stream, x, bt1, 1, 4,
                     NN, 256, 0, xh, xres, (ushort*)nullptr, 0,
                     (const float*)nullptr, (const float*)nullptr,
                     (const float*)nullptr, (const float*)nullptr);
  hipLaunchKernelGGL(k_attn, dim3((NN * 8 + 255) / 256), dim3(256), 0, stream,
                     xh, P, a_src, a_dst);

  // CSR build
  hipLaunchKernelGGL(k_scan_bs, dim3(SCAN_B), dim3(256), 0, stream, count, bsum);
  hipLaunchKernelGGL(k_scan_top, dim3(1), dim3(256), 0, stream, bsum, boff, rowptr);
  hipLaunchKernelGGL(k_scan_wr, dim3(SCAN_B), dim3(256), 0, stream, count, boff, rowptr, rowwork);
  hipLaunchKernelGGL(k_scatter, dim3((EE + 255) / 256), dim3(256), 0, stream,
                     src_c, dst_c, rowwork, perm_src);

  hipLaunchKernelGGL(k_aggregate, dim3(NN / 4), dim3(256), 0, stream, rowptr, perm_src,
                     a_src, a_dst, xh, xres, P + 512, og_b);

  hipLaunchKernelGGL(k_stats_p, dim3(64), dim3(256), 0, stream, og_b, sums1, NN, 256);

  // GEMM2: d_pre = bf16(elu(bn1(og)) @ W_down + b_down)  (BN+ELU fused into A staging)
  hipLaunchKernelGGL(k_gemm, dim3(391), dim3(256), 0, stream, og_b, bt2, 2, 1,
                     NN, 256, 1, (ushort*)nullptr, (ushort*)nullptr, d_pre_b, 64,
                     P + 1280, sums1, P + 768, P + 1024);
  hipLaunchKernelGGL(k_stats_p, dim3(64), dim3(256), 0, stream, d_pre_b, sums2, NN, 64);

  // GEMM3: u_pre = bf16(elu(bn2(d_pre)) @ W_up + b_up)
  hipLaunchKernelGGL(k_gemm, dim3(391), dim3(256), 0, stream, d_pre_b, bt3, 2, 2,
                     NN, 64, 1, (ushort*)nullptr, (ushort*)nullptr, u_pre_b, 256,
                     P + 1472, sums2, P + 1344, P + 1408);
  hipLaunchKernelGGL(k_stats_p, dim3(64), dim3(256), 0, stream, u_pre_b, sums3, NN, 256);

  hipLaunchKernelGGL(k_final, dim3(NN * 256 / 4 / 256), dim3(256), 0, stream,
                     u_pre_b, sums3, og_b, sums1, P, x, d_out);
}

// Round 8
// 610.224 us; speedup vs baseline: 1.0182x; 1.0182x over previous
//
#include <hip/hip_runtime.h>

#define NN 50000
#define EE 800000
#define HEADS 8
#define NEG 0.2f
#define BN_EPS 1e-5f
#define SCAN_B 196   // ceil(NN/256)

typedef unsigned int uint;
typedef unsigned short ushort;

typedef __bf16 bf16x8 __attribute__((ext_vector_type(8)));
typedef float f32x4 __attribute__((ext_vector_type(4)));

__device__ __forceinline__ float bflo(uint u) { return __uint_as_float(u << 16); }
__device__ __forceinline__ float bfhi(uint u) { return __uint_as_float(u & 0xffff0000u); }
__device__ __forceinline__ float bf1(ushort u) { return __uint_as_float(((uint)u) << 16); }
__device__ __forceinline__ ushort f2bf(float f) {
  uint u = __float_as_uint(f);
  u += 0x7fff + ((u >> 16) & 1);   // RTNE
  return (ushort)(u >> 16);
}
__device__ __forceinline__ uint pk2(float a, float b) {
  return (uint)f2bf(a) | ((uint)f2bf(b) << 16);
}
__device__ __forceinline__ float eluf(float v) { return v > 0.f ? v : expm1f(v); }

// ---------------------------------------------------------------- per-block dtype detectors
__device__ __forceinline__ int blk_detect_bf16(const uint* __restrict__ xw) {
  __shared__ int s_bf;
  int t = threadIdx.x;
  if (t < 64) {
    int good = 0;
#pragma unroll
    for (int j = 0; j < 4; ++j) {
      uint lo = xw[t * 4 + j] & 0xffffu;
      uint ex = (lo >> 7) & 0xffu;
      good += (ex >= 110u && ex <= 140u) ? 1 : 0;
    }
    for (int o = 32; o; o >>= 1) good += __shfl_down(good, o);
    if (t == 0) s_bf = (good >= 128) ? 1 : 0;
  }
  __syncthreads();
  return s_bf;
}

__device__ __forceinline__ int blk_detect_i64(const int* __restrict__ ew) {
  __shared__ int s_i64;
  int t = threadIdx.x;
  if (t < 64) {
    int zeros = 0;
#pragma unroll
    for (int j = 0; j < 4; ++j)
      zeros += (ew[2 * (t * 4 + j) + 1] == 0) ? 1 : 0;
    for (int o = 32; o; o >>= 1) zeros += __shfl_down(zeros, o);
    if (t == 0) s_i64 = (zeros >= 200) ? 1 : 0;
  }
  __syncthreads();
  return s_i64;
}

// ---------------------------------------------------------------- prep: params + all weight transposes
// blocks 0..10: param gather -> f32 block P.
// P layout (f32): att_s@0 att_d@256 c_bias@512 g_norm@768 b_norm@1024
//                 b_down@1280 g_down@1344 bb_down@1408 b_up@1472 g_up@1728 bb_up@1984
__global__ __launch_bounds__(256)
void k_prep(const void* __restrict__ x,
            const void* p0, const void* p1, const void* p2, const void* p3,
            const void* p4, const void* p5, const void* p6, const void* p7,
            const void* p8, const void* p9, const void* p10,
            const void* W_lin, const void* W_res, const void* W_down, const void* W_up,
            float* __restrict__ P, ushort* __restrict__ bt1,
            ushort* __restrict__ bt2, ushort* __restrict__ bt3) {
  __shared__ ushort tile[64][65];
  int bf = blk_detect_bf16((const uint*)x);
  int b = blockIdx.x, t = threadIdx.x;
  if (b < 11) {
    const void* srcs[11] = {p0, p1, p2, p3, p4, p5, p6, p7, p8, p9, p10};
    const int sz[11]  = {256, 256, 256, 256, 256, 64, 64, 64, 256, 256, 256};
    const int off[11] = {0, 256, 512, 768, 1024, 1280, 1344, 1408, 1472, 1728, 1984};
    if (t < sz[b]) {
      const void* s = srcs[b];
      P[off[b] + t] = bf ? bf1(((const ushort*)s)[t]) : ((const float*)s)[t];
    }
    return;
  }
  const void* src; ushort* dst; int R, C, D, rb, cb;
  if (b < 27)      { int u = b - 11; src = W_lin;  dst = bt1;         R = 256; C = 256; D = 256; rb = u & 3; cb = u >> 2; }
  else if (b < 43) { int u = b - 27; src = W_res;  dst = bt1 + 65536; R = 256; C = 256; D = 256; rb = u & 3; cb = u >> 2; }
  else if (b < 51) { int u = b - 43; src = W_down; dst = bt2;         R = 256; C = 64;  D = 128; rb = u & 3; cb = u >> 2; }
  else             { int u = b - 51; src = W_up;   dst = bt3;         R = 64;  C = 256; D = 256; rb = 0;     cb = u; }
  int r0 = rb * 64, c0 = cb * 64;
  int tr = t >> 6, tc = t & 63;
#pragma unroll
  for (int i = 0; i < 16; ++i) {
    int rl = tr + i * 4;
    int r = r0 + rl, c = c0 + tc;
    float v = 0.f;
    if (r < R && c < C)
      v = bf ? bf1(((const ushort*)src)[(size_t)r * C + c])
             : ((const float*)src)[(size_t)r * C + c];
    tile[rl][tc] = f2bf(v);
  }
  __syncthreads();
#pragma unroll
  for (int i = 0; i < 16; ++i) {
    int cl = tr + i * 4;
    int rl = tc;
    int c = c0 + cl, r = r0 + rl;
    if (c < D && r < R)
      dst[(size_t)c * R + r] = (c < C) ? tile[rl][cl] : (ushort)0;
  }
}

// ---------------------------------------------------------------- edges -> canonical int32 + degree count
__global__ __launch_bounds__(256)
void k_edges(const int* __restrict__ raw, int* __restrict__ sc, int* __restrict__ dc,
             int* __restrict__ count) {
  int i64 = blk_detect_i64(raw);
  int e = blockIdx.x * 256 + threadIdx.x;
  if (e >= EE) return;
  int s, d;
  if (i64) { s = raw[2 * e]; d = raw[2 * (EE + e)]; }   // int64 lo words
  else     { s = raw[e];     d = raw[EE + e]; }
  if ((uint)s >= NN) s = 0;
  if ((uint)d >= NN) d = 0;
  sc[e] = s; dc[e] = d;
  atomicAdd(&count[d], 1);
}

// ---------------------------------------------------------------- GEMM (MFMA bf16), A-persistent LDS
// C[M,*] = A[M,K] @ Bt[n,K]^T. grid = (m_blocks). The 128-row A-slice is staged into
// LDS ONCE (stride K+8 -> 2-way banks, free), then nIter n-tiles run with ZERO barriers:
// af from LDS, bf straight from global (B is L2-resident, 64-512KB).
// aMode 1: A dtype self-detected (f32 -> convert in staging).
// aMode 2: A bf16 + BN+ELU fused into staging (scale/shift from bnsums/bng/bnb).
// mode 0: bf16 stores split: cols<256 -> o_xh, cols>=256 -> o_xres
// mode 1: bf16 store to o_bf [M,NC] (guard gc<NC) + f32 bias add
__global__ __launch_bounds__(256)
void k_gemm(const void* __restrict__ A, const ushort* __restrict__ Bt,
            int aMode, int nIter, int M, int K, int mode,
            ushort* __restrict__ o_xh, ushort* __restrict__ o_xres,
            ushort* __restrict__ o_bf, int NC, const float* __restrict__ bias,
            const float* __restrict__ bnsums, const float* __restrict__ bng,
            const float* __restrict__ bnb) {
  extern __shared__ __align__(16) ushort Asl[];   // 128*(K+8) ushorts
  __shared__ float scs[256], shs[256];
  int t = threadIdx.x;
  int l = t & 63, w = t >> 6;
  int wr = w >> 1, wc = w & 1;
  int lr = l & 15, lq = l >> 4;
  int m0 = blockIdx.x * 128;
  int stride = K + 8;
  const ushort* Ab = (const ushort*)A;
  const float*  Af = (const float*)A;

  if (aMode == 2 && t < K) {
    const float invN = 1.0f / NN;
    float mean = bnsums[t] * invN;
    float var = bnsums[K + t] * invN - mean * mean;
    float sc = bng[t] * rsqrtf(var + BN_EPS);
    scs[t] = sc;
    shs[t] = bnb[t] - mean * sc;
  }
  __syncthreads();
  int af32 = 0;
  if (aMode == 1) af32 = blk_detect_bf16((const uint*)A) ? 0 : 1;   // has own barrier

  // ---- stage A-slice once
  int W = K >> 3;               // uint4 chunks per row
  int total = 128 * W;
  for (int ci = t; ci < total; ci += 256) {
    int m = ci / W, ko = (ci - m * W) * 8;
    int gm = m0 + m; gm = gm < M ? gm : M - 1;
    uint4 o;
    if (aMode == 1 && af32) {
      float4 u0 = *(const float4*)(Af + (size_t)gm * K + ko);
      float4 u1 = *(const float4*)(Af + (size_t)gm * K + ko + 4);
      o.x = pk2(u0.x, u0.y); o.y = pk2(u0.z, u0.w);
      o.z = pk2(u1.x, u1.y); o.w = pk2(u1.z, u1.w);
    } else {
      uint4 q = *(const uint4*)(Ab + (size_t)gm * K + ko);
      if (aMode == 2) {
        float v0 = eluf(bflo(q.x) * scs[ko + 0] + shs[ko + 0]);
        float v1 = eluf(bfhi(q.x) * scs[ko + 1] + shs[ko + 1]);
        float v2 = eluf(bflo(q.y) * scs[ko + 2] + shs[ko + 2]);
        float v3 = eluf(bfhi(q.y) * scs[ko + 3] + shs[ko + 3]);
        float v4 = eluf(bflo(q.z) * scs[ko + 4] + shs[ko + 4]);
        float v5 = eluf(bfhi(q.z) * scs[ko + 5] + shs[ko + 5]);
        float v6 = eluf(bflo(q.w) * scs[ko + 6] + shs[ko + 6]);
        float v7 = eluf(bfhi(q.w) * scs[ko + 7] + shs[ko + 7]);
        o.x = pk2(v0, v1); o.y = pk2(v2, v3);
        o.z = pk2(v4, v5); o.w = pk2(v6, v7);
      } else {
        o = q;
      }
    }
    *(uint4*)(&Asl[m * stride + ko]) = o;
  }
  __syncthreads();   // last barrier: Asl read-only below

  for (int nc = 0; nc < nIter; ++nc) {
    int n0 = nc * 128;
    f32x4 acc[4][4];
#pragma unroll
    for (int i = 0; i < 4; ++i)
#pragma unroll
      for (int j = 0; j < 4; ++j) acc[i][j] = (f32x4){0.f, 0.f, 0.f, 0.f};

    const ushort* bbase = Bt + (size_t)(n0 + wc * 64 + lr) * K + lq * 8;
    const ushort* arow = &Asl[(wr * 64 + lr) * stride + lq * 8];

    for (int kt = 0; kt < K; kt += 32) {
      bf16x8 af[4], bf[4];
#pragma unroll
      for (int i = 0; i < 4; ++i)
        af[i] = *(const bf16x8*)(arow + i * 16 * stride + kt);
#pragma unroll
      for (int i = 0; i < 4; ++i)
        bf[i] = *(const bf16x8*)(bbase + (size_t)i * 16 * K + kt);
#pragma unroll
      for (int i = 0; i < 4; ++i)
#pragma unroll
        for (int j = 0; j < 4; ++j)
          acc[i][j] = __builtin_amdgcn_mfma_f32_16x16x32_bf16(af[i], bf[j], acc[i][j], 0, 0, 0);
    }

    // C/D layout: col=lane&15, row=(lane>>4)*4+reg  [m89/m91]
#pragma unroll
    for (int i = 0; i < 4; ++i) {
      int gr0 = m0 + wr * 64 + i * 16 + lq * 4;
#pragma unroll
      for (int j = 0; j < 4; ++j) {
        int gc = n0 + wc * 64 + j * 16 + lr;
#pragma unroll
        for (int r = 0; r < 4; ++r) {
          int row = gr0 + r;
          if (row >= M) continue;
          float v = acc[i][j][r];
          if (mode == 0) {
            if (gc < 256) o_xh[(size_t)row * 256 + gc] = f2bf(v);
            else          o_xres[(size_t)row * 256 + (gc - 256)] = f2bf(v);
          } else {
            if (gc < NC) o_bf[(size_t)row * NC + gc] = f2bf(v + bias[gc]);
          }
        }
      }
    }
  }
}

// ---------------------------------------------------------------- attention dots
__global__ void k_attn(const ushort* __restrict__ xh, const float* __restrict__ P,
                       float* __restrict__ a_src, float* __restrict__ a_dst) {
  int id = blockIdx.x * 256 + threadIdx.x;
  if (id >= NN * HEADS) return;
  int n = id >> 3, h = id & 7;
  const uint4* xr = (const uint4*)(xh + (size_t)n * 256 + h * 32);
  const float4* pa = (const float4*)(P + h * 32);
  const float4* pd = (const float4*)(P + 256 + h * 32);
  float s = 0.f, d = 0.f;
#pragma unroll
  for (int j = 0; j < 4; ++j) {
    uint4 q = xr[j];
    float4 a0 = pa[2 * j], a1 = pa[2 * j + 1];
    float4 d0 = pd[2 * j], d1 = pd[2 * j + 1];
    float x0 = bflo(q.x), x1 = bfhi(q.x), x2 = bflo(q.y), x3 = bfhi(q.y);
    float x4 = bflo(q.z), x5 = bfhi(q.z), x6 = bflo(q.w), x7 = bfhi(q.w);
    s += x0 * a0.x + x1 * a0.y + x2 * a0.z + x3 * a0.w
       + x4 * a1.x + x5 * a1.y + x6 * a1.z + x7 * a1.w;
    d += x0 * d0.x + x1 * d0.y + x2 * d0.z + x3 * d0.w
       + x4 * d1.x + x5 * d1.y + x6 * d1.z + x7 * d1.w;
  }
  a_src[id] = s; a_dst[id] = d;
}

// ---------------------------------------------------------------- hierarchical scan (3 kernels)
__global__ void k_scan_bs(const int* __restrict__ count, int* __restrict__ bsum) {
  __shared__ int s[256];
  int i = blockIdx.x * 256 + threadIdx.x;
  s[threadIdx.x] = (i < NN) ? count[i] : 0;
  __syncthreads();
  for (int off = 128; off > 0; off >>= 1) {
    if (threadIdx.x < off) s[threadIdx.x] += s[threadIdx.x + off];
    __syncthreads();
  }
  if (threadIdx.x == 0) bsum[blockIdx.x] = s[0];
}

__global__ void k_scan_top(const int* __restrict__ bsum, int* __restrict__ boff,
                           int* __restrict__ rowptr) {
  __shared__ int s[256];
  int t = threadIdx.x;
  int v = (t < SCAN_B) ? bsum[t] : 0;
  s[t] = v;
  __syncthreads();
  for (int off = 1; off < 256; off <<= 1) {
    int u = (t >= off) ? s[t - off] : 0;
    __syncthreads();
    s[t] += u;
    __syncthreads();
  }
  boff[t] = s[t] - v;
  if (t == 255) rowptr[NN] = s[255];
}

__global__ void k_scan_wr(const int* __restrict__ count, const int* __restrict__ boff,
                          int* __restrict__ rowptr, int* __restrict__ rowwork) {
  __shared__ int s[256];
  int b = blockIdx.x, t = threadIdx.x;
  int i = b * 256 + t;
  int v = (i < NN) ? count[i] : 0;
  s[t] = v;
  __syncthreads();
  for (int off = 1; off < 256; off <<= 1) {
    int u = (t >= off) ? s[t - off] : 0;
    __syncthreads();
    s[t] += u;
    __syncthreads();
  }
  if (i < NN) {
    int ex = boff[b] + s[t] - v;
    rowptr[i] = ex;
    rowwork[i] = ex;
  }
}

// ---------------------------------------------------------------- scatter edges into CSR order
__global__ void k_scatter(const int* __restrict__ sc, const int* __restrict__ dc,
                          int* __restrict__ rowwork, int* __restrict__ perm_src) {
  int e = blockIdx.x * 256 + threadIdx.x;
  if (e >= EE) return;
  int pos = atomicAdd(&rowwork[dc[e]], 1);
  perm_src[pos] = sc[e];
}

// ---------------------------------------------------------------- gather aggregation
__global__ __launch_bounds__(256)
void k_aggregate(const int* __restrict__ rowptr, const int* __restrict__ perm_src,
                 const float* __restrict__ a_src, const float* __restrict__ a_dst,
                 const ushort* __restrict__ xh, const ushort* __restrict__ xres,
                 const float* __restrict__ bias, ushort* __restrict__ outb) {
  int n = blockIdx.x * 4 + (threadIdx.x >> 6);
  int l = threadIdx.x & 63;
  if (n >= NN) return;
  int half = l >> 5;           // 0: even edges, 1: odd edges
  int q = l & 31;              // channels 8q..8q+7
  int h = q >> 2;              // head
  float ad = a_dst[n * 8 + h];
  int st = rowptr[n], en = rowptr[n + 1];
  float a0 = 0.f, a1 = 0.f, a2 = 0.f, a3 = 0.f;
  float a4 = 0.f, a5 = 0.f, a6 = 0.f, a7 = 0.f, sum = 0.f;
  int p = st + half;
  int s_c = 0; float e_c = 0.f; uint4 x_c = {0, 0, 0, 0};
  if (p < en) {
    s_c = perm_src[p];
    e_c = a_src[s_c * 8 + h];
    x_c = *(const uint4*)(xh + (size_t)s_c * 256 + q * 8);
  }
  for (; p < en; p += 2) {
    int pn = p + 2;
    int s_n = 0; float e_n = 0.f; uint4 x_n = {0, 0, 0, 0};
    if (pn < en) {
      s_n = perm_src[pn];
      e_n = a_src[s_n * 8 + h];
      x_n = *(const uint4*)(xh + (size_t)s_n * 256 + q * 8);
    }
    float v = e_c + ad;
    v = v > 0.f ? v : NEG * v;
    float wgt = __expf(fminf(v, 60.f));
    sum += wgt;
    a0 += wgt * bflo(x_c.x); a1 += wgt * bfhi(x_c.x);
    a2 += wgt * bflo(x_c.y); a3 += wgt * bfhi(x_c.y);
    a4 += wgt * bflo(x_c.z); a5 += wgt * bfhi(x_c.z);
    a6 += wgt * bflo(x_c.w); a7 += wgt * bfhi(x_c.w);
    s_c = s_n; e_c = e_n; x_c = x_n;
  }
  sum += __shfl_xor(sum, 32);
  a0 += __shfl_xor(a0, 32); a1 += __shfl_xor(a1, 32);
  a2 += __shfl_xor(a2, 32); a3 += __shfl_xor(a3, 32);
  a4 += __shfl_xor(a4, 32); a5 += __shfl_xor(a5, 32);
  a6 += __shfl_xor(a6, 32); a7 += __shfl_xor(a7, 32);
  if (half == 0) {
    float inv = 1.0f / (sum + 1e-16f);
    int cb = q * 8;
    float4 b0 = *(const float4*)(bias + cb);
    float4 b1 = *(const float4*)(bias + cb + 4);
    uint4 qr = *(const uint4*)(xres + (size_t)n * 256 + cb);
    uint4 pk;
    pk.x = pk2(a0 * inv + b0.x + bflo(qr.x), a1 * inv + b0.y + bfhi(qr.x));
    pk.y = pk2(a2 * inv + b0.z + bflo(qr.y), a3 * inv + b0.w + bfhi(qr.y));
    pk.z = pk2(a4 * inv + b1.x + bflo(qr.z), a5 * inv + b1.y + bfhi(qr.z));
    pk.w = pk2(a6 * inv + b1.z + bflo(qr.w), a7 * inv + b1.w + bfhi(qr.w));
    *(uint4*)(outb + (size_t)n * 256 + cb) = pk;
  }
}

// ---------------------------------------------------------------- BN stats: block partials + 64-way atomic fold
__global__ __launch_bounds__(256)
void k_stats_p(const ushort* __restrict__ x, float* __restrict__ sums, int n, int C) {
  __shared__ float4 redA[256];
  __shared__ float4 redB[256];
  int t = threadIdx.x, b = blockIdx.x;
  int W = C >> 2;
  int c4 = t & (W - 1);
  int rl = t / W;
  int G = 256 / W;
  int rows = (n + 63) / 64;
  int r0 = b * rows, r1 = r0 + rows; if (r1 > n) r1 = n;
  const uint2* xu = (const uint2*)x;
  float s0 = 0, s1 = 0, s2 = 0, s3 = 0, q0 = 0, q1 = 0, q2 = 0, q3 = 0;
  for (int r = r0 + rl; r < r1; r += G) {
    uint2 v = xu[(size_t)r * W + c4];
    float v0 = bflo(v.x), v1 = bfhi(v.x), v2 = bflo(v.y), v3 = bfhi(v.y);
    s0 += v0; s1 += v1; s2 += v2; s3 += v3;
    q0 += v0 * v0; q1 += v1 * v1; q2 += v2 * v2; q3 += v3 * v3;
  }
  redA[t] = make_float4(s0, s1, s2, s3);
  redB[t] = make_float4(q0, q1, q2, q3);
  __syncthreads();
  for (int off = 128; off >= W; off >>= 1) {
    if (t < off) {
      float4 a = redA[t + off], c = redA[t];
      redA[t] = make_float4(c.x + a.x, c.y + a.y, c.z + a.z, c.w + a.w);
      float4 d = redB[t + off], e = redB[t];
      redB[t] = make_float4(e.x + d.x, e.y + d.y, e.z + d.z, e.w + d.w);
    }
    __syncthreads();
  }
  if (t < W) {
    float4 a = redA[t], d = redB[t];
    atomicAdd(&sums[4 * c4 + 0], a.x); atomicAdd(&sums[4 * c4 + 1], a.y);
    atomicAdd(&sums[4 * c4 + 2], a.z); atomicAdd(&sums[4 * c4 + 3], a.w);
    atomicAdd(&sums[C + 4 * c4 + 0], d.x); atomicAdd(&sums[C + 4 * c4 + 1], d.y);
    atomicAdd(&sums[C + 4 * c4 + 2], d.z); atomicAdd(&sums[C + 4 * c4 + 3], d.w);
  }
}

// ---------------------------------------------------------------- out = elu(bn1(og)) + elu(bn3(u_pre)) + x
__global__ void k_final(const ushort* __restrict__ upre, const float* __restrict__ sums3,
                        const ushort* __restrict__ og, const float* __restrict__ sums1,
                        const float* __restrict__ P, const void* __restrict__ xsrc,
                        void* __restrict__ outv) {
  int bf = blk_detect_bf16((const uint*)xsrc);
  int id = blockIdx.x * 256 + threadIdx.x;
  size_t base = (size_t)id * 4;
  if (base >= (size_t)NN * 256) return;
  int c = (int)(base & 255);
  const float invN = 1.0f / NN;
  float4 s3m = *(const float4*)(sums3 + c);
  float4 s3q = *(const float4*)(sums3 + 256 + c);
  float4 g3 = *(const float4*)(P + 1728 + c);
  float4 b3 = *(const float4*)(P + 1984 + c);
  float4 s1m = *(const float4*)(sums1 + c);
  float4 s1q = *(const float4*)(sums1 + 256 + c);
  float4 g1 = *(const float4*)(P + 768 + c);
  float4 b1 = *(const float4*)(P + 1024 + c);
  uint2 qu = *(const uint2*)(upre + base);
  uint2 qo = *(const uint2*)(og + base);
  float xv[4];
  if (bf) {
    uint2 qx = *(const uint2*)((const ushort*)xsrc + base);
    xv[0] = bflo(qx.x); xv[1] = bfhi(qx.x); xv[2] = bflo(qx.y); xv[3] = bfhi(qx.y);
  } else {
    float4 qx = *(const float4*)((const float*)xsrc + base);
    xv[0] = qx.x; xv[1] = qx.y; xv[2] = qx.z; xv[3] = qx.w;
  }
  float uv[4] = {bflo(qu.x), bfhi(qu.x), bflo(qu.y), bfhi(qu.y)};
  float ov[4] = {bflo(qo.x), bfhi(qo.x), bflo(qo.y), bfhi(qo.y)};
  float s3mv[4] = {s3m.x, s3m.y, s3m.z, s3m.w}, s3qv[4] = {s3q.x, s3q.y, s3q.z, s3q.w};
  float g3v[4] = {g3.x, g3.y, g3.z, g3.w}, b3v[4] = {b3.x, b3.y, b3.z, b3.w};
  float s1mv[4] = {s1m.x, s1m.y, s1m.z, s1m.w}, s1qv[4] = {s1q.x, s1q.y, s1q.z, s1q.w};
  float g1v[4] = {g1.x, g1.y, g1.z, g1.w}, b1v[4] = {b1.x, b1.y, b1.z, b1.w};
  float o[4];
#pragma unroll
  for (int j = 0; j < 4; ++j) {
    float m3 = s3mv[j] * invN;
    float v3 = s3qv[j] * invN - m3 * m3;
    float sc3 = g3v[j] * rsqrtf(v3 + BN_EPS);
    float u = eluf((uv[j] - m3) * sc3 + b3v[j]);
    float m1 = s1mv[j] * invN;
    float v1 = s1qv[j] * invN - m1 * m1;
    float sc1 = g1v[j] * rsqrtf(v1 + BN_EPS);
    float h1 = eluf((ov[j] - m1) * sc1 + b1v[j]);
    o[j] = u + h1 + xv[j];
  }
  if (bf) {
    uint2 pk;
    pk.x = pk2(o[0], o[1]);
    pk.y = pk2(o[2], o[3]);
    *(uint2*)((ushort*)outv + base) = pk;
  } else {
    *(float4*)((float*)outv + base) = make_float4(o[0], o[1], o[2], o[3]);
  }
}

// ================================================================ host
extern "C" void kernel_launch(void* const* d_in, const int* in_sizes, int n_in,
                              void* d_out, int out_size, void* d_ws, size_t ws_size,
                              hipStream_t stream) {
  const void* x      = d_in[0];
  const int*  ei     = (const int*)d_in[1];
  const void* W_lin  = d_in[2];
  const void* att_s  = d_in[3];
  const void* att_d  = d_in[4];
  const void* c_bias = d_in[5];
  const void* W_res  = d_in[6];
  const void* g_norm = d_in[7];
  const void* b_norm = d_in[8];
  const void* W_down = d_in[9];
  const void* b_down = d_in[10];
  const void* g_down = d_in[11];
  const void* bb_down= d_in[12];
  const void* W_up   = d_in[13];
  const void* b_up   = d_in[14];
  const void* g_up   = d_in[15];
  const void* bb_up  = d_in[16];

  char* ws = (char*)d_ws;
  size_t off = 0;
  auto alloc = [&](size_t bytes) -> char* {
    char* p = ws + off;
    off = (off + bytes + 255) & ~(size_t)255;
    return p;
  };
  // ---- zeroed region (atomic accumulators)
  int*   count  = (int*)alloc((size_t)NN * 4);
  float* sums1  = (float*)alloc(512 * 4);
  float* sums2  = (float*)alloc(128 * 4);
  float* sums3  = (float*)alloc(512 * 4);
  size_t zbytes = off;
  // ---- rest
  float* P      = (float*)alloc(2240 * 4);
  int* bsum     = (int*)alloc(256 * 4);
  int* boff     = (int*)alloc(256 * 4);
  int* rowptr   = (int*)alloc((size_t)(NN + 1) * 4);
  int* rowwork  = (int*)alloc((size_t)(NN + 1) * 4);
  int* src_c    = (int*)alloc((size_t)EE * 4);
  int* dst_c    = (int*)alloc((size_t)EE * 4);
  int* perm_src = (int*)alloc((size_t)EE * 4);
  ushort* bt1   = (ushort*)alloc((size_t)512 * 256 * 2);
  ushort* bt2   = (ushort*)alloc((size_t)128 * 256 * 2);  // rows 64..127 zero-padded
  ushort* bt3   = (ushort*)alloc((size_t)256 * 64 * 2);
  float* a_src  = (float*)alloc((size_t)NN * 8 * 4);
  float* a_dst  = (float*)alloc((size_t)NN * 8 * 4);
  ushort* xh    = (ushort*)alloc((size_t)NN * 256 * 2);
  ushort* xres  = (ushort*)alloc((size_t)NN * 256 * 2);
  ushort* og_b  = (ushort*)alloc((size_t)NN * 256 * 2);   // GAT output bf16 (lives to k_final)
  // ---- aliases (non-overlapping lifetimes)
  ushort* d_pre_b = xh;    // xh dead after k_aggregate; GEMM2 output [NN,64]
  ushort* u_pre_b = xres;  // xres dead after k_aggregate; GEMM3 output [NN,256]

  hipMemsetAsync(d_ws, 0, zbytes, stream);

  hipLaunchKernelGGL(k_prep, dim3(55), dim3(256), 0, stream, x,
                     att_s, att_d, c_bias, g_norm, b_norm, b_down, g_down, bb_down,
                     b_up, g_up, bb_up, W_lin, W_res, W_down, W_up, P, bt1, bt2, bt3);
  hipLaunchKernelGGL(k_edges, dim3((EE + 255) / 256), dim3(256), 0, stream,
                     ei, src_c, dst_c, count);

  const size_t lds256 = 128 * (256 + 8) * 2;   // 67584 B
  const size_t lds64  = 128 * (64 + 8) * 2;    // 18432 B

  // GEMM1: [xh | xres] = x @ [W_lin | W_res]  (A staged to LDS once; barrier-free K-loop)
  hipLaunchKernelGGL(k_gemm, dim3(391), dim3(256), lds256, stream, x, bt1, 1, 4,
                     NN, 256, 0, xh, xres, (ushort*)nullptr, 0,
                     (const float*)nullptr, (const float*)nullptr,
                     (const float*)nullptr, (const float*)nullptr);
  hipLaunchKernelGGL(k_attn, dim3((NN * 8 + 255) / 256), dim3(256), 0, stream,
                     xh, P, a_src, a_dst);

  // CSR build
  hipLaunchKernelGGL(k_scan_bs, dim3(SCAN_B), dim3(256), 0, stream, count, bsum);
  hipLaunchKernelGGL(k_scan_top, dim3(1), dim3(256), 0, stream, bsum, boff, rowptr);
  hipLaunchKernelGGL(k_scan_wr, dim3(SCAN_B), dim3(256), 0, stream, count, boff, rowptr, rowwork);
  hipLaunchKernelGGL(k_scatter, dim3((EE + 255) / 256), dim3(256), 0, stream,
                     src_c, dst_c, rowwork, perm_src);

  hipLaunchKernelGGL(k_aggregate, dim3(NN / 4), dim3(256), 0, stream, rowptr, perm_src,
                     a_src, a_dst, xh, xres, P + 512, og_b);

  hipLaunchKernelGGL(k_stats_p, dim3(64), dim3(256), 0, stream, og_b, sums1, NN, 256);

  // GEMM2: d_pre = bf16(elu(bn1(og)) @ W_down + b_down)
  hipLaunchKernelGGL(k_gemm, dim3(391), dim3(256), lds256, stream, og_b, bt2, 2, 1,
                     NN, 256, 1, (ushort*)nullptr, (ushort*)nullptr, d_pre_b, 64,
                     P + 1280, sums1, P + 768, P + 1024);
  hipLaunchKernelGGL(k_stats_p, dim3(64), dim3(256), 0, stream, d_pre_b, sums2, NN, 64);

  // GEMM3: u_pre = bf16(elu(bn2(d_pre)) @ W_up + b_up)
  hipLaunchKernelGGL(k_gemm, dim3(391), dim3(256), lds64, stream, d_pre_b, bt3, 2, 2,
                     NN, 64, 1, (ushort*)nullptr, (ushort*)nullptr, u_pre_b, 256,
                     P + 1472, sums2, P + 1344, P + 1408);
  hipLaunchKernelGGL(k_stats_p, dim3(64), dim3(256), 0, stream, u_pre_b, sums3, NN, 256);

  hipLaunchKernelGGL(k_final, dim3(NN * 256 / 4 / 256), dim3(256), 0, stream,
                     u_pre_b, sums3, og_b, sums1, P, x, d_out);
}

// Round 9
// 603.493 us; speedup vs baseline: 1.0296x; 1.0112x over previous
//
#include <hip/hip_runtime.h>

#define NN 50000
#define EE 800000
#define HEADS 8
#define NEG 0.2f
#define BN_EPS 1e-5f
#define SCAN_B 196   // ceil(NN/256)

typedef unsigned int uint;
typedef unsigned short ushort;

typedef __bf16 bf16x8 __attribute__((ext_vector_type(8)));
typedef float f32x4 __attribute__((ext_vector_type(4)));

__device__ __forceinline__ float bflo(uint u) { return __uint_as_float(u << 16); }
__device__ __forceinline__ float bfhi(uint u) { return __uint_as_float(u & 0xffff0000u); }
__device__ __forceinline__ float bf1(ushort u) { return __uint_as_float(((uint)u) << 16); }
__device__ __forceinline__ ushort f2bf(float f) {
  uint u = __float_as_uint(f);
  u += 0x7fff + ((u >> 16) & 1);   // RTNE
  return (ushort)(u >> 16);
}
__device__ __forceinline__ uint pk2(float a, float b) {
  return (uint)f2bf(a) | ((uint)f2bf(b) << 16);
}
__device__ __forceinline__ float eluf(float v) { return v > 0.f ? v : expm1f(v); }

// ---------------------------------------------------------------- per-block dtype detectors
__device__ __forceinline__ int blk_detect_bf16(const uint* __restrict__ xw) {
  __shared__ int s_bf;
  int t = threadIdx.x;
  if (t < 64) {
    int good = 0;
#pragma unroll
    for (int j = 0; j < 4; ++j) {
      uint lo = xw[t * 4 + j] & 0xffffu;
      uint ex = (lo >> 7) & 0xffu;
      good += (ex >= 110u && ex <= 140u) ? 1 : 0;
    }
    for (int o = 32; o; o >>= 1) good += __shfl_down(good, o);
    if (t == 0) s_bf = (good >= 128) ? 1 : 0;
  }
  __syncthreads();
  return s_bf;
}

__device__ __forceinline__ int blk_detect_i64(const int* __restrict__ ew) {
  __shared__ int s_i64;
  int t = threadIdx.x;
  if (t < 64) {
    int zeros = 0;
#pragma unroll
    for (int j = 0; j < 4; ++j)
      zeros += (ew[2 * (t * 4 + j) + 1] == 0) ? 1 : 0;
    for (int o = 32; o; o >>= 1) zeros += __shfl_down(zeros, o);
    if (t == 0) s_i64 = (zeros >= 200) ? 1 : 0;
  }
  __syncthreads();
  return s_i64;
}

// ---------------------------------------------------------------- prep: params + all weight transposes
// P layout (f32): att_s@0 att_d@256 c_bias@512 g_norm@768 b_norm@1024
//                 b_down@1280 g_down@1344 bb_down@1408 b_up@1472 g_up@1728 bb_up@1984
__global__ __launch_bounds__(256)
void k_prep(const void* __restrict__ x,
            const void* p0, const void* p1, const void* p2, const void* p3,
            const void* p4, const void* p5, const void* p6, const void* p7,
            const void* p8, const void* p9, const void* p10,
            const void* W_lin, const void* W_res, const void* W_down, const void* W_up,
            float* __restrict__ P, ushort* __restrict__ bt1,
            ushort* __restrict__ bt2, ushort* __restrict__ bt3) {
  __shared__ ushort tile[64][65];
  int bf = blk_detect_bf16((const uint*)x);
  int b = blockIdx.x, t = threadIdx.x;
  if (b < 11) {
    const void* srcs[11] = {p0, p1, p2, p3, p4, p5, p6, p7, p8, p9, p10};
    const int sz[11]  = {256, 256, 256, 256, 256, 64, 64, 64, 256, 256, 256};
    const int off[11] = {0, 256, 512, 768, 1024, 1280, 1344, 1408, 1472, 1728, 1984};
    if (t < sz[b]) {
      const void* s = srcs[b];
      P[off[b] + t] = bf ? bf1(((const ushort*)s)[t]) : ((const float*)s)[t];
    }
    return;
  }
  const void* src; ushort* dst; int R, C, D, rb, cb;
  if (b < 27)      { int u = b - 11; src = W_lin;  dst = bt1;         R = 256; C = 256; D = 256; rb = u & 3; cb = u >> 2; }
  else if (b < 43) { int u = b - 27; src = W_res;  dst = bt1 + 65536; R = 256; C = 256; D = 256; rb = u & 3; cb = u >> 2; }
  else if (b < 51) { int u = b - 43; src = W_down; dst = bt2;         R = 256; C = 64;  D = 128; rb = u & 3; cb = u >> 2; }
  else             { int u = b - 51; src = W_up;   dst = bt3;         R = 64;  C = 256; D = 256; rb = 0;     cb = u; }
  int r0 = rb * 64, c0 = cb * 64;
  int tr = t >> 6, tc = t & 63;
#pragma unroll
  for (int i = 0; i < 16; ++i) {
    int rl = tr + i * 4;
    int r = r0 + rl, c = c0 + tc;
    float v = 0.f;
    if (r < R && c < C)
      v = bf ? bf1(((const ushort*)src)[(size_t)r * C + c])
             : ((const float*)src)[(size_t)r * C + c];
    tile[rl][tc] = f2bf(v);
  }
  __syncthreads();
#pragma unroll
  for (int i = 0; i < 16; ++i) {
    int cl = tr + i * 4;
    int rl = tc;
    int c = c0 + cl, r = r0 + rl;
    if (c < D && r < R)
      dst[(size_t)c * R + r] = (c < C) ? tile[rl][cl] : (ushort)0;
  }
}

// ---------------------------------------------------------------- edges -> canonical int32 + degree count
__global__ __launch_bounds__(256)
void k_edges(const int* __restrict__ raw, int* __restrict__ sc, int* __restrict__ dc,
             int* __restrict__ count) {
  int i64 = blk_detect_i64(raw);
  int e = blockIdx.x * 256 + threadIdx.x;
  if (e >= EE) return;
  int s, d;
  if (i64) {
    uint2 qs = *(const uint2*)(raw + 2 * e);
    uint2 qd = *(const uint2*)(raw + 2 * (EE + e));
    s = (int)qs.x; d = (int)qd.x;
  } else {
    s = raw[e]; d = raw[EE + e];
  }
  if ((uint)s >= NN) s = 0;
  if ((uint)d >= NN) d = 0;
  sc[e] = s; dc[e] = d;
  atomicAdd(&count[d], 1);
}

// ---------------------------------------------------------------- GEMM (MFMA bf16), A-persistent LDS
// C[M,*] = A[M,K] @ Bt[n,K]^T. grid = (m_blocks). 128-row A-slice staged into LDS ONCE
// (stride K+8), then nIter n-tiles run barrier-free: af from LDS, bf from global (L2-resident).
// aMode 1: A dtype self-detected (f32 -> convert in staging).
// aMode 2: A bf16 + BN+ELU fused into staging.
// mode 0: bf16 stores split: cols<256 -> o_xh, cols>=256 -> o_xres
// mode 1: bf16 store to o_bf [M,NC] (guard gc<NC) + f32 bias add
__global__ __launch_bounds__(256)
void k_gemm(const void* __restrict__ A, const ushort* __restrict__ Bt,
            int aMode, int nIter, int M, int K, int mode,
            ushort* __restrict__ o_xh, ushort* __restrict__ o_xres,
            ushort* __restrict__ o_bf, int NC, const float* __restrict__ bias,
            const float* __restrict__ bnsums, const float* __restrict__ bng,
            const float* __restrict__ bnb) {
  extern __shared__ __align__(16) ushort Asl[];   // 128*(K+8) ushorts
  __shared__ float scs[256], shs[256];
  int t = threadIdx.x;
  int l = t & 63, w = t >> 6;
  int wr = w >> 1, wc = w & 1;
  int lr = l & 15, lq = l >> 4;
  int m0 = blockIdx.x * 128;
  int stride = K + 8;
  const ushort* Ab = (const ushort*)A;
  const float*  Af = (const float*)A;

  if (aMode == 2 && t < K) {
    const float invN = 1.0f / NN;
    float mean = bnsums[t] * invN;
    float var = bnsums[K + t] * invN - mean * mean;
    float sc = bng[t] * rsqrtf(var + BN_EPS);
    scs[t] = sc;
    shs[t] = bnb[t] - mean * sc;
  }
  __syncthreads();
  int af32 = 0;
  if (aMode == 1) af32 = blk_detect_bf16((const uint*)A) ? 0 : 1;   // has own barrier

  // ---- stage A-slice once
  int W = K >> 3;               // uint4 chunks per row
  int total = 128 * W;
  for (int ci = t; ci < total; ci += 256) {
    int m = ci / W, ko = (ci - m * W) * 8;
    int gm = m0 + m; gm = gm < M ? gm : M - 1;
    uint4 o;
    if (aMode == 1 && af32) {
      float4 u0 = *(const float4*)(Af + (size_t)gm * K + ko);
      float4 u1 = *(const float4*)(Af + (size_t)gm * K + ko + 4);
      o.x = pk2(u0.x, u0.y); o.y = pk2(u0.z, u0.w);
      o.z = pk2(u1.x, u1.y); o.w = pk2(u1.z, u1.w);
    } else {
      uint4 q = *(const uint4*)(Ab + (size_t)gm * K + ko);
      if (aMode == 2) {
        float v0 = eluf(bflo(q.x) * scs[ko + 0] + shs[ko + 0]);
        float v1 = eluf(bfhi(q.x) * scs[ko + 1] + shs[ko + 1]);
        float v2 = eluf(bflo(q.y) * scs[ko + 2] + shs[ko + 2]);
        float v3 = eluf(bfhi(q.y) * scs[ko + 3] + shs[ko + 3]);
        float v4 = eluf(bflo(q.z) * scs[ko + 4] + shs[ko + 4]);
        float v5 = eluf(bfhi(q.z) * scs[ko + 5] + shs[ko + 5]);
        float v6 = eluf(bflo(q.w) * scs[ko + 6] + shs[ko + 6]);
        float v7 = eluf(bfhi(q.w) * scs[ko + 7] + shs[ko + 7]);
        o.x = pk2(v0, v1); o.y = pk2(v2, v3);
        o.z = pk2(v4, v5); o.w = pk2(v6, v7);
      } else {
        o = q;
      }
    }
    *(uint4*)(&Asl[m * stride + ko]) = o;
  }
  __syncthreads();   // last barrier: Asl read-only below

  for (int nc = 0; nc < nIter; ++nc) {
    int n0 = nc * 128;
    f32x4 acc[4][4];
#pragma unroll
    for (int i = 0; i < 4; ++i)
#pragma unroll
      for (int j = 0; j < 4; ++j) acc[i][j] = (f32x4){0.f, 0.f, 0.f, 0.f};

    const ushort* bbase = Bt + (size_t)(n0 + wc * 64 + lr) * K + lq * 8;
    const ushort* arow = &Asl[(wr * 64 + lr) * stride + lq * 8];

    for (int kt = 0; kt < K; kt += 32) {
      bf16x8 af[4], bf[4];
#pragma unroll
      for (int i = 0; i < 4; ++i)
        af[i] = *(const bf16x8*)(arow + i * 16 * stride + kt);
#pragma unroll
      for (int i = 0; i < 4; ++i)
        bf[i] = *(const bf16x8*)(bbase + (size_t)i * 16 * K + kt);
#pragma unroll
      for (int i = 0; i < 4; ++i)
#pragma unroll
        for (int j = 0; j < 4; ++j)
          acc[i][j] = __builtin_amdgcn_mfma_f32_16x16x32_bf16(af[i], bf[j], acc[i][j], 0, 0, 0);
    }

    // C/D layout: col=lane&15, row=(lane>>4)*4+reg  [m89/m91]
#pragma unroll
    for (int i = 0; i < 4; ++i) {
      int gr0 = m0 + wr * 64 + i * 16 + lq * 4;
#pragma unroll
      for (int j = 0; j < 4; ++j) {
        int gc = n0 + wc * 64 + j * 16 + lr;
#pragma unroll
        for (int r = 0; r < 4; ++r) {
          int row = gr0 + r;
          if (row >= M) continue;
          float v = acc[i][j][r];
          if (mode == 0) {
            if (gc < 256) o_xh[(size_t)row * 256 + gc] = f2bf(v);
            else          o_xres[(size_t)row * 256 + (gc - 256)] = f2bf(v);
          } else {
            if (gc < NC) o_bf[(size_t)row * NC + gc] = f2bf(v + bias[gc]);
          }
        }
      }
    }
  }
}

// ---------------------------------------------------------------- attention dots
__global__ void k_attn(const ushort* __restrict__ xh, const float* __restrict__ P,
                       float* __restrict__ a_src, float* __restrict__ a_dst) {
  int id = blockIdx.x * 256 + threadIdx.x;
  if (id >= NN * HEADS) return;
  int n = id >> 3, h = id & 7;
  const uint4* xr = (const uint4*)(xh + (size_t)n * 256 + h * 32);
  const float4* pa = (const float4*)(P + h * 32);
  const float4* pd = (const float4*)(P + 256 + h * 32);
  float s = 0.f, d = 0.f;
#pragma unroll
  for (int j = 0; j < 4; ++j) {
    uint4 q = xr[j];
    float4 a0 = pa[2 * j], a1 = pa[2 * j + 1];
    float4 d0 = pd[2 * j], d1 = pd[2 * j + 1];
    float x0 = bflo(q.x), x1 = bfhi(q.x), x2 = bflo(q.y), x3 = bfhi(q.y);
    float x4 = bflo(q.z), x5 = bfhi(q.z), x6 = bflo(q.w), x7 = bfhi(q.w);
    s += x0 * a0.x + x1 * a0.y + x2 * a0.z + x3 * a0.w
       + x4 * a1.x + x5 * a1.y + x6 * a1.z + x7 * a1.w;
    d += x0 * d0.x + x1 * d0.y + x2 * d0.z + x3 * d0.w
       + x4 * d1.x + x5 * d1.y + x6 * d1.z + x7 * d1.w;
  }
  a_src[id] = s; a_dst[id] = d;
}

// ---------------------------------------------------------------- hierarchical scan (3 kernels)
__global__ void k_scan_bs(const int* __restrict__ count, int* __restrict__ bsum) {
  __shared__ int s[256];
  int i = blockIdx.x * 256 + threadIdx.x;
  s[threadIdx.x] = (i < NN) ? count[i] : 0;
  __syncthreads();
  for (int off = 128; off > 0; off >>= 1) {
    if (threadIdx.x < off) s[threadIdx.x] += s[threadIdx.x + off];
    __syncthreads();
  }
  if (threadIdx.x == 0) bsum[blockIdx.x] = s[0];
}

__global__ void k_scan_top(const int* __restrict__ bsum, int* __restrict__ boff,
                           int* __restrict__ rowptr) {
  __shared__ int s[256];
  int t = threadIdx.x;
  int v = (t < SCAN_B) ? bsum[t] : 0;
  s[t] = v;
  __syncthreads();
  for (int off = 1; off < 256; off <<= 1) {
    int u = (t >= off) ? s[t - off] : 0;
    __syncthreads();
    s[t] += u;
    __syncthreads();
  }
  boff[t] = s[t] - v;
  if (t == 255) rowptr[NN] = s[255];
}

__global__ void k_scan_wr(const int* __restrict__ count, const int* __restrict__ boff,
                          int* __restrict__ rowptr, int* __restrict__ rowwork) {
  __shared__ int s[256];
  int b = blockIdx.x, t = threadIdx.x;
  int i = b * 256 + t;
  int v = (i < NN) ? count[i] : 0;
  s[t] = v;
  __syncthreads();
  for (int off = 1; off < 256; off <<= 1) {
    int u = (t >= off) ? s[t - off] : 0;
    __syncthreads();
    s[t] += u;
    __syncthreads();
  }
  if (i < NN) {
    int ex = boff[b] + s[t] - v;
    rowptr[i] = ex;
    rowwork[i] = ex;
  }
}

// ---------------------------------------------------------------- scatter edges into CSR order
__global__ void k_scatter(const int* __restrict__ sc, const int* __restrict__ dc,
                          int* __restrict__ rowwork, int* __restrict__ perm_src) {
  int e = blockIdx.x * 256 + threadIdx.x;
  if (e >= EE) return;
  int pos = atomicAdd(&rowwork[dc[e]], 1);
  perm_src[pos] = sc[e];
}

// ---------------------------------------------------------------- gather aggregation
// wave per dst node; FOUR quarter-wave edge streams (g=l>>4), lane owns 16 channels
// (32B = 2x uint4 per edge) -> 16 uint4 loads in flight per wave. 1-deep prefetch.
__global__ __launch_bounds__(256)
void k_aggregate(const int* __restrict__ rowptr, const int* __restrict__ perm_src,
                 const float* __restrict__ a_src, const float* __restrict__ a_dst,
                 const ushort* __restrict__ xh, const ushort* __restrict__ xres,
                 const float* __restrict__ bias, ushort* __restrict__ outb) {
  int n = blockIdx.x * 4 + (threadIdx.x >> 6);
  int l = threadIdx.x & 63;
  if (n >= NN) return;
  int g = l >> 4;              // edge stream 0..3
  int q = l & 15;              // channels 16q .. 16q+15
  int h = q >> 1;              // head
  float ad = a_dst[n * 8 + h];
  int st = rowptr[n], en = rowptr[n + 1];
  float a[16];
#pragma unroll
  for (int k = 0; k < 16; ++k) a[k] = 0.f;
  float sum = 0.f;

  int p = st + g;
  bool have = p < en;
  float e_c = 0.f;
  uint4 xc0 = {0, 0, 0, 0}, xc1 = {0, 0, 0, 0};
  if (have) {
    int s0 = perm_src[p];
    e_c = a_src[s0 * 8 + h];
    const ushort* xp = xh + (size_t)s0 * 256 + q * 16;
    xc0 = *(const uint4*)xp;
    xc1 = *(const uint4*)(xp + 8);
  }
  while (have) {
    int pn = p + 4;
    bool hn = pn < en;
    float e_n = 0.f;
    uint4 xn0 = {0, 0, 0, 0}, xn1 = {0, 0, 0, 0};
    if (hn) {
      int s1 = perm_src[pn];
      e_n = a_src[s1 * 8 + h];
      const ushort* xp = xh + (size_t)s1 * 256 + q * 16;
      xn0 = *(const uint4*)xp;
      xn1 = *(const uint4*)(xp + 8);
    }
    float v = e_c + ad;
    v = v > 0.f ? v : NEG * v;
    float wgt = __expf(fminf(v, 60.f));
    sum += wgt;
    a[0] += wgt * bflo(xc0.x);  a[1] += wgt * bfhi(xc0.x);
    a[2] += wgt * bflo(xc0.y);  a[3] += wgt * bfhi(xc0.y);
    a[4] += wgt * bflo(xc0.z);  a[5] += wgt * bfhi(xc0.z);
    a[6] += wgt * bflo(xc0.w);  a[7] += wgt * bfhi(xc0.w);
    a[8] += wgt * bflo(xc1.x);  a[9] += wgt * bfhi(xc1.x);
    a[10] += wgt * bflo(xc1.y); a[11] += wgt * bfhi(xc1.y);
    a[12] += wgt * bflo(xc1.z); a[13] += wgt * bfhi(xc1.z);
    a[14] += wgt * bflo(xc1.w); a[15] += wgt * bfhi(xc1.w);
    p = pn; have = hn; e_c = e_n; xc0 = xn0; xc1 = xn1;
  }
  // combine the 4 streams (lanes l, l^16, l^32, l^48 share q)
  sum += __shfl_xor(sum, 16);
  sum += __shfl_xor(sum, 32);
#pragma unroll
  for (int k = 0; k < 16; ++k) {
    a[k] += __shfl_xor(a[k], 16);
    a[k] += __shfl_xor(a[k], 32);
  }
  if (g == 0) {
    float inv = 1.0f / (sum + 1e-16f);
    int cb = q * 16;
    float4 b0 = *(const float4*)(bias + cb);
    float4 b1 = *(const float4*)(bias + cb + 4);
    float4 b2 = *(const float4*)(bias + cb + 8);
    float4 b3 = *(const float4*)(bias + cb + 12);
    uint4 r0 = *(const uint4*)(xres + (size_t)n * 256 + cb);
    uint4 r1 = *(const uint4*)(xres + (size_t)n * 256 + cb + 8);
    uint4 o0, o1;
    o0.x = pk2(a[0] * inv + b0.x + bflo(r0.x),  a[1] * inv + b0.y + bfhi(r0.x));
    o0.y = pk2(a[2] * inv + b0.z + bflo(r0.y),  a[3] * inv + b0.w + bfhi(r0.y));
    o0.z = pk2(a[4] * inv + b1.x + bflo(r0.z),  a[5] * inv + b1.y + bfhi(r0.z));
    o0.w = pk2(a[6] * inv + b1.z + bflo(r0.w),  a[7] * inv + b1.w + bfhi(r0.w));
    o1.x = pk2(a[8] * inv + b2.x + bflo(r1.x),  a[9] * inv + b2.y + bfhi(r1.x));
    o1.y = pk2(a[10] * inv + b2.z + bflo(r1.y), a[11] * inv + b2.w + bfhi(r1.y));
    o1.z = pk2(a[12] * inv + b3.x + bflo(r1.z), a[13] * inv + b3.y + bfhi(r1.z));
    o1.w = pk2(a[14] * inv + b3.z + bflo(r1.w), a[15] * inv + b3.w + bfhi(r1.w));
    *(uint4*)(outb + (size_t)n * 256 + cb) = o0;
    *(uint4*)(outb + (size_t)n * 256 + cb + 8) = o1;
  }
}

// ---------------------------------------------------------------- BN stats: block partials + 64-way atomic fold
__global__ __launch_bounds__(256)
void k_stats_p(const ushort* __restrict__ x, float* __restrict__ sums, int n, int C) {
  __shared__ float4 redA[256];
  __shared__ float4 redB[256];
  int t = threadIdx.x, b = blockIdx.x;
  int W = C >> 2;
  int c4 = t & (W - 1);
  int rl = t / W;
  int G = 256 / W;
  int rows = (n + 63) / 64;
  int r0 = b * rows, r1 = r0 + rows; if (r1 > n) r1 = n;
  const uint2* xu = (const uint2*)x;
  float s0 = 0, s1 = 0, s2 = 0, s3 = 0, q0 = 0, q1 = 0, q2 = 0, q3 = 0;
  for (int r = r0 + rl; r < r1; r += G) {
    uint2 v = xu[(size_t)r * W + c4];
    float v0 = bflo(v.x), v1 = bfhi(v.x), v2 = bflo(v.y), v3 = bfhi(v.y);
    s0 += v0; s1 += v1; s2 += v2; s3 += v3;
    q0 += v0 * v0; q1 += v1 * v1; q2 += v2 * v2; q3 += v3 * v3;
  }
  redA[t] = make_float4(s0, s1, s2, s3);
  redB[t] = make_float4(q0, q1, q2, q3);
  __syncthreads();
  for (int off = 128; off >= W; off >>= 1) {
    if (t < off) {
      float4 a = redA[t + off], c = redA[t];
      redA[t] = make_float4(c.x + a.x, c.y + a.y, c.z + a.z, c.w + a.w);
      float4 d = redB[t + off], e = redB[t];
      redB[t] = make_float4(e.x + d.x, e.y + d.y, e.z + d.z, e.w + d.w);
    }
    __syncthreads();
  }
  if (t < W) {
    float4 a = redA[t], d = redB[t];
    atomicAdd(&sums[4 * c4 + 0], a.x); atomicAdd(&sums[4 * c4 + 1], a.y);
    atomicAdd(&sums[4 * c4 + 2], a.z); atomicAdd(&sums[4 * c4 + 3], a.w);
    atomicAdd(&sums[C + 4 * c4 + 0], d.x); atomicAdd(&sums[C + 4 * c4 + 1], d.y);
    atomicAdd(&sums[C + 4 * c4 + 2], d.z); atomicAdd(&sums[C + 4 * c4 + 3], d.w);
  }
}

// ---------------------------------------------------------------- out = elu(bn1(og)) + elu(bn3(u_pre)) + x
__global__ void k_final(const ushort* __restrict__ upre, const float* __restrict__ sums3,
                        const ushort* __restrict__ og, const float* __restrict__ sums1,
                        const float* __restrict__ P, const void* __restrict__ xsrc,
                        void* __restrict__ outv) {
  int bf = blk_detect_bf16((const uint*)xsrc);
  int id = blockIdx.x * 256 + threadIdx.x;
  size_t base = (size_t)id * 4;
  if (base >= (size_t)NN * 256) return;
  int c = (int)(base & 255);
  const float invN = 1.0f / NN;
  float4 s3m = *(const float4*)(sums3 + c);
  float4 s3q = *(const float4*)(sums3 + 256 + c);
  float4 g3 = *(const float4*)(P + 1728 + c);
  float4 b3 = *(const float4*)(P + 1984 + c);
  float4 s1m = *(const float4*)(sums1 + c);
  float4 s1q = *(const float4*)(sums1 + 256 + c);
  float4 g1 = *(const float4*)(P + 768 + c);
  float4 b1 = *(const float4*)(P + 1024 + c);
  uint2 qu = *(const uint2*)(upre + base);
  uint2 qo = *(const uint2*)(og + base);
  float xv[4];
  if (bf) {
    uint2 qx = *(const uint2*)((const ushort*)xsrc + base);
    xv[0] = bflo(qx.x); xv[1] = bfhi(qx.x); xv[2] = bflo(qx.y); xv[3] = bfhi(qx.y);
  } else {
    float4 qx = *(const float4*)((const float*)xsrc + base);
    xv[0] = qx.x; xv[1] = qx.y; xv[2] = qx.z; xv[3] = qx.w;
  }
  float uv[4] = {bflo(qu.x), bfhi(qu.x), bflo(qu.y), bfhi(qu.y)};
  float ov[4] = {bflo(qo.x), bfhi(qo.x), bflo(qo.y), bfhi(qo.y)};
  float s3mv[4] = {s3m.x, s3m.y, s3m.z, s3m.w}, s3qv[4] = {s3q.x, s3q.y, s3q.z, s3q.w};
  float g3v[4] = {g3.x, g3.y, g3.z, g3.w}, b3v[4] = {b3.x, b3.y, b3.z, b3.w};
  float s1mv[4] = {s1m.x, s1m.y, s1m.z, s1m.w}, s1qv[4] = {s1q.x, s1q.y, s1q.z, s1q.w};
  float g1v[4] = {g1.x, g1.y, g1.z, g1.w}, b1v[4] = {b1.x, b1.y, b1.z, b1.w};
  float o[4];
#pragma unroll
  for (int j = 0; j < 4; ++j) {
    float m3 = s3mv[j] * invN;
    float v3 = s3qv[j] * invN - m3 * m3;
    float sc3 = g3v[j] * rsqrtf(v3 + BN_EPS);
    float u = eluf((uv[j] - m3) * sc3 + b3v[j]);
    float m1 = s1mv[j] * invN;
    float v1 = s1qv[j] * invN - m1 * m1;
    float sc1 = g1v[j] * rsqrtf(v1 + BN_EPS);
    float h1 = eluf((ov[j] - m1) * sc1 + b1v[j]);
    o[j] = u + h1 + xv[j];
  }
  if (bf) {
    uint2 pk;
    pk.x = pk2(o[0], o[1]);
    pk.y = pk2(o[2], o[3]);
    *(uint2*)((ushort*)outv + base) = pk;
  } else {
    *(float4*)((float*)outv + base) = make_float4(o[0], o[1], o[2], o[3]);
  }
}

// ================================================================ host
extern "C" void kernel_launch(void* const* d_in, const int* in_sizes, int n_in,
                              void* d_out, int out_size, void* d_ws, size_t ws_size,
                              hipStream_t stream) {
  const void* x      = d_in[0];
  const int*  ei     = (const int*)d_in[1];
  const void* W_lin  = d_in[2];
  const void* att_s  = d_in[3];
  const void* att_d  = d_in[4];
  const void* c_bias = d_in[5];
  const void* W_res  = d_in[6];
  const void* g_norm = d_in[7];
  const void* b_norm = d_in[8];
  const void* W_down = d_in[9];
  const void* b_down = d_in[10];
  const void* g_down = d_in[11];
  const void* bb_down= d_in[12];
  const void* W_up   = d_in[13];
  const void* b_up   = d_in[14];
  const void* g_up   = d_in[15];
  const void* bb_up  = d_in[16];

  char* ws = (char*)d_ws;
  size_t off = 0;
  auto alloc = [&](size_t bytes) -> char* {
    char* p = ws + off;
    off = (off + bytes + 255) & ~(size_t)255;
    return p;
  };
  // ---- zeroed region (atomic accumulators)
  int*   count  = (int*)alloc((size_t)NN * 4);
  float* sums1  = (float*)alloc(512 * 4);
  float* sums2  = (float*)alloc(128 * 4);
  float* sums3  = (float*)alloc(512 * 4);
  size_t zbytes = off;
  // ---- rest
  float* P      = (float*)alloc(2240 * 4);
  int* bsum     = (int*)alloc(256 * 4);
  int* boff     = (int*)alloc(256 * 4);
  int* rowptr   = (int*)alloc((size_t)(NN + 1) * 4);
  int* rowwork  = (int*)alloc((size_t)(NN + 1) * 4);
  int* src_c    = (int*)alloc((size_t)EE * 4);
  int* dst_c    = (int*)alloc((size_t)EE * 4);
  int* perm_src = (int*)alloc((size_t)EE * 4);
  ushort* bt1   = (ushort*)alloc((size_t)512 * 256 * 2);
  ushort* bt2   = (ushort*)alloc((size_t)128 * 256 * 2);  // rows 64..127 zero-padded
  ushort* bt3   = (ushort*)alloc((size_t)256 * 64 * 2);
  float* a_src  = (float*)alloc((size_t)NN * 8 * 4);
  float* a_dst  = (float*)alloc((size_t)NN * 8 * 4);
  ushort* xh    = (ushort*)alloc((size_t)NN * 256 * 2);
  ushort* xres  = (ushort*)alloc((size_t)NN * 256 * 2);
  ushort* og_b  = (ushort*)alloc((size_t)NN * 256 * 2);   // GAT output bf16 (lives to k_final)
  // ---- aliases (non-overlapping lifetimes)
  ushort* d_pre_b = xh;    // xh dead after k_aggregate; GEMM2 output [NN,64]
  ushort* u_pre_b = xres;  // xres dead after k_aggregate; GEMM3 output [NN,256]

  hipMemsetAsync(d_ws, 0, zbytes, stream);

  hipLaunchKernelGGL(k_prep, dim3(55), dim3(256), 0, stream, x,
                     att_s, att_d, c_bias, g_norm, b_norm, b_down, g_down, bb_down,
                     b_up, g_up, bb_up, W_lin, W_res, W_down, W_up, P, bt1, bt2, bt3);
  hipLaunchKernelGGL(k_edges, dim3((EE + 255) / 256), dim3(256), 0, stream,
                     ei, src_c, dst_c, count);

  const size_t lds256 = 128 * (256 + 8) * 2;   // 67584 B
  const size_t lds64  = 128 * (64 + 8) * 2;    // 18432 B

  // GEMM1: [xh | xres] = x @ [W_lin | W_res]
  hipLaunchKernelGGL(k_gemm, dim3(391), dim3(256), lds256, stream, x, bt1, 1, 4,
                     NN, 256, 0, xh, xres, (ushort*)nullptr, 0,
                     (const float*)nullptr, (const float*)nullptr,
                     (const float*)nullptr, (const float*)nullptr);
  hipLaunchKernelGGL(k_attn, dim3((NN * 8 + 255) / 256), dim3(256), 0, stream,
                     xh, P, a_src, a_dst);

  // CSR build
  hipLaunchKernelGGL(k_scan_bs, dim3(SCAN_B), dim3(256), 0, stream, count, bsum);
  hipLaunchKernelGGL(k_scan_top, dim3(1), dim3(256), 0, stream, bsum, boff, rowptr);
  hipLaunchKernelGGL(k_scan_wr, dim3(SCAN_B), dim3(256), 0, stream, count, boff, rowptr, rowwork);
  hipLaunchKernelGGL(k_scatter, dim3((EE + 255) / 256), dim3(256), 0, stream,
                     src_c, dst_c, rowwork, perm_src);

  hipLaunchKernelGGL(k_aggregate, dim3(NN / 4), dim3(256), 0, stream, rowptr, perm_src,
                     a_src, a_dst, xh, xres, P + 512, og_b);

  hipLaunchKernelGGL(k_stats_p, dim3(64), dim3(256), 0, stream, og_b, sums1, NN, 256);

  // GEMM2: d_pre = bf16(elu(bn1(og)) @ W_down + b_down)
  hipLaunchKernelGGL(k_gemm, dim3(391), dim3(256), lds256, stream, og_b, bt2, 2, 1,
                     NN, 256, 1, (ushort*)nullptr, (ushort*)nullptr, d_pre_b, 64,
                     P + 1280, sums1, P + 768, P + 1024);
  hipLaunchKernelGGL(k_stats_p, dim3(64), dim3(256), 0, stream, d_pre_b, sums2, NN, 64);

  // GEMM3: u_pre = bf16(elu(bn2(d_pre)) @ W_up + b_up)
  hipLaunchKernelGGL(k_gemm, dim3(391), dim3(256), lds64, stream, d_pre_b, bt3, 2, 2,
                     NN, 64, 1, (ushort*)nullptr, (ushort*)nullptr, u_pre_b, 256,
                     P + 1472, sums2, P + 1344, P + 1408);
  hipLaunchKernelGGL(k_stats_p, dim3(64), dim3(256), 0, stream, u_pre_b, sums3, NN, 256);

  hipLaunchKernelGGL(k_final, dim3(NN * 256 / 4 / 256), dim3(256), 0, stream,
                     u_pre_b, sums3, og_b, sums1, P, x, d_out);
}